// Round 6
// baseline (335.398 us; speedup 1.0000x reference)
//
#include <hip/hip_runtime.h>

// ---------------------------------------------------------------------------
// B=4, H=W=64, N=4096, C=512, nh=8, hd=64, SR=2, Nk=1024. scale = 0.125.
// No-max exp2 softmax: logits are O(0.5) (weights *0.02) -> exact in fp32.
// ---------------------------------------------------------------------------

typedef __attribute__((ext_vector_type(8)))  short short8;      // 8 bf16 frag
typedef __attribute__((ext_vector_type(8)))  unsigned short ushort8;
typedef __attribute__((ext_vector_type(4)))  float floatx4;
typedef __attribute__((ext_vector_type(16))) float floatx16;

__device__ inline unsigned short bf16r(float f) {   // RNE float->bf16
    union { float f; unsigned u; } v; v.f = f;
    unsigned r = v.u + 0x7fffu + ((v.u >> 16) & 1u);
    return (unsigned short)(r >> 16);
}

__device__ inline ushort8 pack8(float4 a, float4 b) {
    ushort8 o;
    o[0] = bf16r(a.x); o[1] = bf16r(a.y); o[2] = bf16r(a.z); o[3] = bf16r(a.w);
    o[4] = bf16r(b.x); o[5] = bf16r(b.y); o[6] = bf16r(b.z); o[7] = bf16r(b.w);
    return o;
}

__device__ inline void gl_lds16(const void* g, void* l) {
    __builtin_amdgcn_global_load_lds(
        (const __attribute__((address_space(1))) unsigned int*)g,
        (__attribute__((address_space(3))) unsigned int*)l, 16, 0, 0);
}

// ---------------------------------------------------------------------------
// Fused fp32->bf16 convert for x + all four weights (q_w folded w/ 0.125*log2e)
// ---------------------------------------------------------------------------
__global__ __launch_bounds__(256)
void convert_all(const float* __restrict__ x,  const float* __restrict__ qw,
                 const float* __restrict__ kvw, const float* __restrict__ srw,
                 const float* __restrict__ pw,
                 unsigned short* __restrict__ xb,  unsigned short* __restrict__ qwb,
                 unsigned short* __restrict__ kvwb, unsigned short* __restrict__ srwb,
                 unsigned short* __restrict__ pwb) {
    const int bid = blockIdx.x;
    const float* src; unsigned short* dst; int off; float sc = 1.f;
    if (bid < 4096)      { src = x;   dst = xb;   off = bid * 256; }
    else if (bid < 4224) { src = qw;  dst = qwb;  off = (bid - 4096) * 256;
                           sc = 0.18033688011112042f; /* 0.125*log2(e) */ }
    else if (bid < 4480) { src = kvw; dst = kvwb; off = (bid - 4224) * 256; }
    else if (bid < 4992) { src = srw; dst = srwb; off = (bid - 4480) * 256; }
    else                 { src = pw;  dst = pwb;  off = (bid - 4992) * 256; }
    const int idx = off + threadIdx.x;
    float4 a = *(const float4*)(src + (size_t)idx * 8);
    float4 b = *(const float4*)(src + (size_t)idx * 8 + 4);
    a.x *= sc; a.y *= sc; a.z *= sc; a.w *= sc;
    b.x *= sc; b.y *= sc; b.z *= sc; b.w *= sc;
    *(ushort8*)(dst + (size_t)idx * 8) = pack8(a, b);
}

// bf16 im2col for SR=2 conv (reads fp32 x). xrb[m][k], k = c*4 + di*2 + dj.
__global__ __launch_bounds__(256)
void gather_xr_f32(const float* __restrict__ x, unsigned short* __restrict__ xrb) {
    const int idx = blockIdx.x * 256 + threadIdx.x;   // < 4096*512
    const int c = idx & 511;
    const int m = idx >> 9;
    const int b = m >> 10;
    const int rem = m & 1023;
    const int oi = rem >> 5, oj = rem & 31;
    const int n00 = oi * 128 + oj * 2;
    const float* base = x + ((size_t)b * 4096) * 512 + c;
    const unsigned long long v00 = bf16r(base[(size_t)(n00)      * 512]);
    const unsigned long long v01 = bf16r(base[(size_t)(n00 + 1)  * 512]);
    const unsigned long long v10 = bf16r(base[(size_t)(n00 + 64) * 512]);
    const unsigned long long v11 = bf16r(base[(size_t)(n00 + 65) * 512]);
    const unsigned long long w = v00 | (v01 << 16) | (v10 << 32) | (v11 << 48);
    *(unsigned long long*)(xrb + (size_t)m * 2048 + c * 4) = w;
}

// ---------------------------------------------------------------------------
// MFMA GEMM: C[M,N] = A[M,K] @ B[N,K]^T (+bias). BM x 128 tile, BK=32,
// 256 thr = 4 waves. MODE: 0 = fp32 out row-major; 1 = bf16 out row-major
// (paired u32 stores via shfl); 2 = Kt mode (A=K-weights, rows=c, cols=key:
// write Kb[bh][key][d] with r-quad b64 packs); 3 = Vt mode (rows=key,
// cols=c: write Vt[bh][d][key] with r-quad b64 packs).
// ---------------------------------------------------------------------------
template<int BM, int MODE>
__global__ __launch_bounds__(256)
void gemm_mfma(const unsigned short* __restrict__ A,
               const unsigned short* __restrict__ B,
               const float* __restrict__ bias,
               float* __restrict__ Cf, unsigned short* __restrict__ Cb,
               int M, int N, int K) {
    constexpr int MI = BM / 32;
    __shared__ unsigned short As[BM * 32];
    __shared__ unsigned short Bs[128 * 32];
    const int t = threadIdx.x;
    const int w = t >> 6, l = t & 63;
    const int lq = l & 15, quad = l >> 4;
    const int bm = blockIdx.x * BM, bn = blockIdx.y * 128;
    const int wrow = (w >> 1) * (BM / 2), wcol = (w & 1) * 64;

    floatx4 acc[MI][4];
    #pragma unroll
    for (int mi = 0; mi < MI; ++mi)
        #pragma unroll
        for (int ni = 0; ni < 4; ++ni) acc[mi][ni] = (floatx4){0.f, 0.f, 0.f, 0.f};

    for (int k0 = 0; k0 < K; k0 += 32) {
        __syncthreads();
        #pragma unroll
        for (int i = 0; i < BM / 64; ++i) {
            const int c = i * 256 + t;
            gl_lds16(A + (size_t)(bm + (c >> 2)) * K + k0 + (c & 3) * 8, &As[c * 8]);
        }
        #pragma unroll
        for (int i = 0; i < 2; ++i) {
            const int c = i * 256 + t;
            gl_lds16(B + (size_t)(bn + (c >> 2)) * K + k0 + (c & 3) * 8, &Bs[c * 8]);
        }
        __syncthreads();

        short8 bf[4];
        #pragma unroll
        for (int ni = 0; ni < 4; ++ni)
            bf[ni] = *(const short8*)&Bs[(wcol + ni * 16 + lq) * 32 + quad * 8];
        #pragma unroll
        for (int mi = 0; mi < MI; ++mi) {
            const short8 af = *(const short8*)&As[(wrow + mi * 16 + lq) * 32 + quad * 8];
            #pragma unroll
            for (int ni = 0; ni < 4; ++ni)
                acc[mi][ni] = __builtin_amdgcn_mfma_f32_16x16x32_bf16(
                    af, bf[ni], acc[mi][ni], 0, 0, 0);
        }
    }

    #pragma unroll
    for (int ni = 0; ni < 4; ++ni) {
        const int col = bn + wcol + ni * 16 + lq;
        const float bv = (MODE <= 1 && bias) ? bias[col] : 0.f;
        #pragma unroll
        for (int mi = 0; mi < MI; ++mi) {
            const int row0 = bm + wrow + mi * 16 + quad * 4;
            if (MODE == 0) {
                #pragma unroll
                for (int r = 0; r < 4; ++r)
                    Cf[(size_t)(row0 + r) * N + col] = acc[mi][ni][r] + bv;
            } else if (MODE == 1) {
                unsigned own[4], mg[4];
                #pragma unroll
                for (int r = 0; r < 4; ++r) own[r] = bf16r(acc[mi][ni][r] + bv);
                #pragma unroll
                for (int r = 0; r < 4; ++r) {
                    const unsigned pt = __shfl_xor(own[r], 1);
                    mg[r] = (lq & 1) ? (pt | (own[r] << 16)) : (own[r] | (pt << 16));
                }
                const int colb = bn + wcol + ni * 16 + (lq & ~1);
                const int rb = (lq & 1) * 2;
                *(unsigned*)(Cb + (size_t)(row0 + rb)     * N + colb) = mg[rb];
                *(unsigned*)(Cb + (size_t)(row0 + rb + 1) * N + colb) = mg[rb + 1];
            } else if (MODE == 2) {
                const int kb = col >> 10, key = col & 1023;
                const int h = row0 >> 6, d0 = row0 & 63;
                unsigned long long wv = 0;
                #pragma unroll
                for (int r = 0; r < 4; ++r)
                    wv |= (unsigned long long)bf16r(acc[mi][ni][r]) << (16 * r);
                *(unsigned long long*)(Cb +
                    (((size_t)(kb * 8 + h)) * 1024 + key) * 64 + d0) = wv;
            } else {
                const int kb = row0 >> 10, key0 = row0 & 1023;
                const int h = col >> 6, d = col & 63;
                unsigned long long wv = 0;
                #pragma unroll
                for (int r = 0; r < 4; ++r)
                    wv |= (unsigned long long)bf16r(acc[mi][ni][r]) << (16 * r);
                *(unsigned long long*)(Cb +
                    (((size_t)(kb * 8 + h)) * 64 + d) * 1024 + key0) = wv;
            }
        }
    }
}

// ---------------------------------------------------------------------------
// MFMA flash attention v3: ZERO LDS, ZERO barriers. Each lane loads its
// K/V MFMA fragments directly from global (Kb[bh][key][d] rows are exactly
// A-frag runs; Vt[bh][d][key] rows are exactly B-frag runs; both 16B
// contiguous). K/V per bh = 256KB, re-read by 32 q-blocks -> L2-resident.
// No barriers => compiler software-pipelines next-tile loads into current
// compute. P stays in registers (C->A transform = one shfl_xor(32)/chunk).
// ---------------------------------------------------------------------------
__global__ __launch_bounds__(256)
void attn_direct(const unsigned short* __restrict__ qb,
                 const unsigned short* __restrict__ Kb,
                 const unsigned short* __restrict__ Vt,
                 unsigned short* __restrict__ out) {
    const int t = threadIdx.x;
    const int w = t >> 6;
    const int lane = t & 63;
    const int m32 = lane & 31;     // q-col (S^T) / key-row (K A-frag) / d-col (O)
    const int sig = lane >> 5;     // half-lane
    const int n0 = blockIdx.x * 128;
    const int bh = blockIdx.y;
    const int b = bh >> 3, h = bh & 7;

    // Q B-frags (held all kernel), pre-scaled by 0.125*log2e at convert time
    short8 qf[4];
    {
        const unsigned short* qrow =
            qb + ((size_t)(b * 4096 + n0 + w * 32 + m32)) * 512 + h * 64;
        #pragma unroll
        for (int kc = 0; kc < 4; ++kc)
            qf[kc] = *(const short8*)(qrow + kc * 16 + sig * 8);
    }

    float l_own = 0.f;
    floatx16 O0, O1;
    #pragma unroll
    for (int i = 0; i < 16; ++i) { O0[i] = 0.f; O1[i] = 0.f; }

    const unsigned short* Kg = Kb + (size_t)bh * 1024 * 64;
    const unsigned short* Vg = Vt + (size_t)bh * 64 * 1024;

    for (int kt = 0; kt < 16; ++kt) {
        // direct-global fragment loads (16B each, no LDS round-trip)
        short8 ka0[4], ka1[4], va0[4], va1[4];
        #pragma unroll
        for (int kc = 0; kc < 4; ++kc) {
            ka0[kc] = *(const short8*)(Kg + (size_t)(kt * 64 + m32)      * 64 + kc * 16 + sig * 8);
            ka1[kc] = *(const short8*)(Kg + (size_t)(kt * 64 + 32 + m32) * 64 + kc * 16 + sig * 8);
            va0[kc] = *(const short8*)(Vg + (size_t)(m32)      * 1024 + kt * 64 + kc * 16 + sig * 8);
            va1[kc] = *(const short8*)(Vg + (size_t)(32 + m32) * 1024 + kt * 64 + kc * 16 + sig * 8);
        }

        // S^T = K·Q^T : two 32-key groups
        floatx16 st0, st1;
        #pragma unroll
        for (int i = 0; i < 16; ++i) { st0[i] = 0.f; st1[i] = 0.f; }
        #pragma unroll
        for (int kc = 0; kc < 4; ++kc) {
            st0 = __builtin_amdgcn_mfma_f32_32x32x16_bf16(ka0[kc], qf[kc], st0, 0, 0, 0);
            st1 = __builtin_amdgcn_mfma_f32_32x32x16_bf16(ka1[kc], qf[kc], st1, 0, 0, 0);
        }

        // p = 2^s, truncated-bf16 pack per reg-quad; l from truncated values
        uint2 E[2][4];
        #pragma unroll
        for (int g = 0; g < 2; ++g) {
            #pragma unroll
            for (int qd = 0; qd < 4; ++qd) {
                const float s0 = g ? st1[qd * 4 + 0] : st0[qd * 4 + 0];
                const float s1 = g ? st1[qd * 4 + 1] : st0[qd * 4 + 1];
                const float s2 = g ? st1[qd * 4 + 2] : st0[qd * 4 + 2];
                const float s3 = g ? st1[qd * 4 + 3] : st0[qd * 4 + 3];
                const unsigned u0 = __float_as_uint(__builtin_amdgcn_exp2f(s0));
                const unsigned u1 = __float_as_uint(__builtin_amdgcn_exp2f(s1));
                const unsigned u2 = __float_as_uint(__builtin_amdgcn_exp2f(s2));
                const unsigned u3 = __float_as_uint(__builtin_amdgcn_exp2f(s3));
                E[g][qd].x = __builtin_amdgcn_perm(u1, u0, 0x07060302u);
                E[g][qd].y = __builtin_amdgcn_perm(u3, u2, 0x07060302u);
                l_own += __uint_as_float(u0 & 0xffff0000u)
                       + __uint_as_float(u1 & 0xffff0000u)
                       + __uint_as_float(u2 & 0xffff0000u)
                       + __uint_as_float(u3 & 0xffff0000u);
            }
        }

        // O += P·V : A-frag per K-chunk via one cross-half exchange.
        #pragma unroll
        for (int kc = 0; kc < 4; ++kc) {
            const int g = kc >> 1, qlo = (kc & 1) * 2;
            const uint2 keep = sig ? E[g][qlo + 1] : E[g][qlo];
            const uint2 send = sig ? E[g][qlo]     : E[g][qlo + 1];
            uint2 got;
            got.x = __shfl_xor(send.x, 32);
            got.y = __shfl_xor(send.y, 32);
            uint4 fr;
            fr.x = sig ? got.x  : keep.x;
            fr.y = sig ? got.y  : keep.y;
            fr.z = sig ? keep.x : got.x;
            fr.w = sig ? keep.y : got.y;
            const short8 pa = *(const short8*)&fr;
            O0 = __builtin_amdgcn_mfma_f32_32x32x16_bf16(pa, va0[kc], O0, 0, 0, 0);
            O1 = __builtin_amdgcn_mfma_f32_32x32x16_bf16(pa, va1[kc], O1, 0, 0, 0);
        }
    }

    // combine key-halves of l
    l_own += __shfl_xor(l_own, 32);
    const float inv = 1.0f / l_own;

    float fo0[16], fo1[16];
    #pragma unroll
    for (int r = 0; r < 16; ++r) {
        const float li = __shfl(inv, ((r & 3) + 8 * (r >> 2)) + 4 * sig);
        fo0[r] = O0[r] * li;
        fo1[r] = O1[r] * li;
    }

    // paired u32 bf16 stores: even m32 stores gd=0 regs, odd stores gd=1
    #pragma unroll
    for (int gd = 0; gd < 2; ++gd) {
        unsigned mg[16];
        #pragma unroll
        for (int r = 0; r < 16; ++r) {
            const unsigned own = bf16r(gd ? fo1[r] : fo0[r]);
            const unsigned pt = __shfl_xor(own, 1);
            mg[r] = (m32 & 1) ? (pt | (own << 16)) : (own | (pt << 16));
        }
        if ((m32 & 1) == gd) {
            const int colb = h * 64 + gd * 32 + (m32 & ~1);
            #pragma unroll
            for (int r = 0; r < 16; ++r) {
                const int qrow = (r & 3) + 8 * (r >> 2) + 4 * sig;
                const size_t row = (size_t)(b * 4096 + n0 + w * 32 + qrow);
                *(unsigned*)(out + row * 512 + colb) = mg[r];
            }
        }
    }
}

extern "C" void kernel_launch(void* const* d_in, const int* in_sizes, int n_in,
                              void* d_out, int out_size, void* d_ws, size_t ws_size,
                              hipStream_t stream) {
    const float* x      = (const float*)d_in[0];
    const float* q_w    = (const float*)d_in[1];
    const float* kv_w   = (const float*)d_in[2];
    const float* sr_w   = (const float*)d_in[3];
    const float* sr_b   = (const float*)d_in[4];
    const float* proj_w = (const float*)d_in[5];
    const float* proj_b = (const float*)d_in[6];
    float* out = (float*)d_out;

    // Workspace (ushort = bf16). xb dead after q-gemm -> reused as attb.
    unsigned short* xb   = (unsigned short*)d_ws;               // 16384*512
    unsigned short* attb = xb;
    unsigned short* qb   = xb   + (size_t)16384 * 512;          // 16384*512
    unsigned short* xrb  = qb   + (size_t)16384 * 512;          // 4096*2048
    unsigned short* xsrb = xrb  + (size_t)4096 * 2048;          // 4096*512
    unsigned short* qwb  = xsrb + (size_t)4096 * 512;           // 512*512
    unsigned short* kvwb = qwb  + (size_t)512 * 512;            // 1024*512
    unsigned short* srwb = kvwb + (size_t)1024 * 512;           // 512*2048
    unsigned short* pwb  = srwb + (size_t)512 * 2048;           // 512*512
    unsigned short* Kb   = pwb  + (size_t)512 * 512;            // 32*1024*64
    unsigned short* Vt   = Kb   + (size_t)32 * 1024 * 64;       // 32*64*1024
    // total ~72 MB

    const dim3 blk(256);

    convert_all<<<5120, blk, 0, stream>>>(x, q_w, kv_w, sr_w, proj_w,
                                          xb, qwb, kvwb, srwb, pwb);

    gather_xr_f32<<<8192, blk, 0, stream>>>(x, xrb);

    // q = x @ (scaled q_w)^T -> bf16
    gemm_mfma<128, 1><<<dim3(128, 4), blk, 0, stream>>>(
        xb, qwb, nullptr, nullptr, qb, 16384, 512, 512);

    // x_sr = conv(x) + sr_b -> bf16   (BM=64 => 256 blocks)
    gemm_mfma<64, 1><<<dim3(64, 4), blk, 0, stream>>>(
        xrb, srwb, sr_b, nullptr, xsrb, 4096, 512, 2048);

    // K = (kv_w_K @ x_sr^T): rows=c, cols=key -> Kb[bh][key][d] (b64 packs)
    gemm_mfma<128, 2><<<dim3(4, 32), blk, 0, stream>>>(
        kvwb, xsrb, nullptr, nullptr, Kb, 512, 4096, 512);

    // V = x_sr @ kv_w_V^T: rows=key, cols=c -> Vt[bh][d][key] (b64 packs)
    gemm_mfma<128, 3><<<dim3(32, 4), blk, 0, stream>>>(
        xsrb, kvwb + (size_t)512 * 512, nullptr, nullptr, Vt, 4096, 512, 512);

    // attention -> bf16 att (aliases xb)
    attn_direct<<<dim3(32, 32), blk, 0, stream>>>(qb, Kb, Vt, attb);

    // out = att @ proj_w^T + proj_b -> fp32
    gemm_mfma<128, 0><<<dim3(128, 4), blk, 0, stream>>>(
        attb, pwb, proj_b, out, nullptr, 16384, 512, 512);
}

// Round 7
// 245.135 us; speedup vs baseline: 1.3682x; 1.3682x over previous
//
#include <hip/hip_runtime.h>

// ---------------------------------------------------------------------------
// B=4, H=W=64, N=4096, C=512, nh=8, hd=64, SR=2, Nk=1024. scale = 0.125.
// No-max exp2 softmax: logits are O(0.5) (weights *0.02) -> exact in fp32.
// ---------------------------------------------------------------------------

typedef __attribute__((ext_vector_type(8)))  short short8;      // 8 bf16 frag
typedef __attribute__((ext_vector_type(8)))  unsigned short ushort8;
typedef __attribute__((ext_vector_type(4)))  float floatx4;
typedef __attribute__((ext_vector_type(16))) float floatx16;

__device__ inline unsigned short bf16r(float f) {   // RNE float->bf16
    union { float f; unsigned u; } v; v.f = f;
    unsigned r = v.u + 0x7fffu + ((v.u >> 16) & 1u);
    return (unsigned short)(r >> 16);
}

__device__ inline ushort8 pack8(float4 a, float4 b) {
    ushort8 o;
    o[0] = bf16r(a.x); o[1] = bf16r(a.y); o[2] = bf16r(a.z); o[3] = bf16r(a.w);
    o[4] = bf16r(b.x); o[5] = bf16r(b.y); o[6] = bf16r(b.z); o[7] = bf16r(b.w);
    return o;
}

__device__ inline void gl_lds16(const void* g, void* l) {
    __builtin_amdgcn_global_load_lds(
        (const __attribute__((address_space(1))) unsigned int*)g,
        (__attribute__((address_space(3))) unsigned int*)l, 16, 0, 0);
}

// ---------------------------------------------------------------------------
// prep: fused fp32->bf16 converts (x + 4 weights; q_w folded w/ 0.125*log2e)
// PLUS the bf16 im2col for the SR=2 conv. One launch.
//   blocks [0,5120): converts ; blocks [5120,13312): im2col
// ---------------------------------------------------------------------------
__global__ __launch_bounds__(256)
void prep(const float* __restrict__ x,  const float* __restrict__ qw,
          const float* __restrict__ kvw, const float* __restrict__ srw,
          const float* __restrict__ pw,
          unsigned short* __restrict__ xb,  unsigned short* __restrict__ qwb,
          unsigned short* __restrict__ kvwb, unsigned short* __restrict__ srwb,
          unsigned short* __restrict__ pwb, unsigned short* __restrict__ xrb) {
    const int bid = blockIdx.x;
    if (bid < 5120) {
        const float* src; unsigned short* dst; int off; float sc = 1.f;
        if (bid < 4096)      { src = x;   dst = xb;   off = bid * 256; }
        else if (bid < 4224) { src = qw;  dst = qwb;  off = (bid - 4096) * 256;
                               sc = 0.18033688011112042f; /* 0.125*log2(e) */ }
        else if (bid < 4480) { src = kvw; dst = kvwb; off = (bid - 4224) * 256; }
        else if (bid < 4992) { src = srw; dst = srwb; off = (bid - 4480) * 256; }
        else                 { src = pw;  dst = pwb;  off = (bid - 4992) * 256; }
        const int idx = off + threadIdx.x;
        float4 a = *(const float4*)(src + (size_t)idx * 8);
        float4 b = *(const float4*)(src + (size_t)idx * 8 + 4);
        a.x *= sc; a.y *= sc; a.z *= sc; a.w *= sc;
        b.x *= sc; b.y *= sc; b.z *= sc; b.w *= sc;
        *(ushort8*)(dst + (size_t)idx * 8) = pack8(a, b);
    } else {
        const int idx = (bid - 5120) * 256 + threadIdx.x;   // < 4096*512
        const int c = idx & 511;
        const int m = idx >> 9;
        const int b = m >> 10;
        const int rem = m & 1023;
        const int oi = rem >> 5, oj = rem & 31;
        const int n00 = oi * 128 + oj * 2;
        const float* base = x + ((size_t)b * 4096) * 512 + c;
        const unsigned long long v00 = bf16r(base[(size_t)(n00)      * 512]);
        const unsigned long long v01 = bf16r(base[(size_t)(n00 + 1)  * 512]);
        const unsigned long long v10 = bf16r(base[(size_t)(n00 + 64) * 512]);
        const unsigned long long v11 = bf16r(base[(size_t)(n00 + 65) * 512]);
        const unsigned long long w = v00 | (v01 << 16) | (v10 << 32) | (v11 << 48);
        *(unsigned long long*)(xrb + (size_t)m * 2048 + c * 4) = w;
    }
}

// ---------------------------------------------------------------------------
// MFMA GEMM: C[M,N] = A[M,K] @ B[N,K]^T (+bias). BM x BN tile, BK=32,
// 256 thr = 4 waves. BN=128: waves 2x2 (64x64 each). BN=64: waves 4x1
// stacked in M (each BM/4 x 64) -> 2x the blocks for short-K occupancy.
// MODE: 0 fp32 out; 1 bf16 out (paired u32 stores); 2 Kt mode (rows=c,
// cols=key -> Kb[bh][key][d] b64 packs); 3 Vt mode (rows=key, cols=c ->
// Vt[bh][d][key] b64 packs).
// ---------------------------------------------------------------------------
template<int BM, int BN, int MODE>
__global__ __launch_bounds__(256)
void gemm_mfma(const unsigned short* __restrict__ A,
               const unsigned short* __restrict__ B,
               const float* __restrict__ bias,
               float* __restrict__ Cf, unsigned short* __restrict__ Cb,
               int M, int N, int K) {
    constexpr int WR = (BN == 128) ? BM / 2 : BM / 4;   // rows per wave
    constexpr int MI = WR / 16;
    __shared__ unsigned short As[BM * 32];
    __shared__ unsigned short Bs[BN * 32];
    const int t = threadIdx.x;
    const int w = t >> 6, l = t & 63;
    const int lq = l & 15, quad = l >> 4;
    const int bm = blockIdx.x * BM, bn = blockIdx.y * BN;
    const int wrow = (BN == 128) ? (w >> 1) * (BM / 2) : w * (BM / 4);
    const int wcol = (BN == 128) ? (w & 1) * 64 : 0;

    floatx4 acc[MI][4];
    #pragma unroll
    for (int mi = 0; mi < MI; ++mi)
        #pragma unroll
        for (int ni = 0; ni < 4; ++ni) acc[mi][ni] = (floatx4){0.f, 0.f, 0.f, 0.f};

    for (int k0 = 0; k0 < K; k0 += 32) {
        __syncthreads();
        #pragma unroll
        for (int i = 0; i < BM / 64; ++i) {
            const int c = i * 256 + t;
            gl_lds16(A + (size_t)(bm + (c >> 2)) * K + k0 + (c & 3) * 8, &As[c * 8]);
        }
        #pragma unroll
        for (int i = 0; i < BN / 64; ++i) {
            const int c = i * 256 + t;
            gl_lds16(B + (size_t)(bn + (c >> 2)) * K + k0 + (c & 3) * 8, &Bs[c * 8]);
        }
        __syncthreads();

        short8 bf[4];
        #pragma unroll
        for (int ni = 0; ni < 4; ++ni)
            bf[ni] = *(const short8*)&Bs[(wcol + ni * 16 + lq) * 32 + quad * 8];
        #pragma unroll
        for (int mi = 0; mi < MI; ++mi) {
            const short8 af = *(const short8*)&As[(wrow + mi * 16 + lq) * 32 + quad * 8];
            #pragma unroll
            for (int ni = 0; ni < 4; ++ni)
                acc[mi][ni] = __builtin_amdgcn_mfma_f32_16x16x32_bf16(
                    af, bf[ni], acc[mi][ni], 0, 0, 0);
        }
    }

    #pragma unroll
    for (int ni = 0; ni < 4; ++ni) {
        const int col = bn + wcol + ni * 16 + lq;
        const float bv = (MODE <= 1 && bias) ? bias[col] : 0.f;
        #pragma unroll
        for (int mi = 0; mi < MI; ++mi) {
            const int row0 = bm + wrow + mi * 16 + quad * 4;
            if (MODE == 0) {
                #pragma unroll
                for (int r = 0; r < 4; ++r)
                    Cf[(size_t)(row0 + r) * N + col] = acc[mi][ni][r] + bv;
            } else if (MODE == 1) {
                unsigned own[4], mg[4];
                #pragma unroll
                for (int r = 0; r < 4; ++r) own[r] = bf16r(acc[mi][ni][r] + bv);
                #pragma unroll
                for (int r = 0; r < 4; ++r) {
                    const unsigned pt = __shfl_xor(own[r], 1);
                    mg[r] = (lq & 1) ? (pt | (own[r] << 16)) : (own[r] | (pt << 16));
                }
                const int colb = bn + wcol + ni * 16 + (lq & ~1);
                const int rb = (lq & 1) * 2;
                *(unsigned*)(Cb + (size_t)(row0 + rb)     * N + colb) = mg[rb];
                *(unsigned*)(Cb + (size_t)(row0 + rb + 1) * N + colb) = mg[rb + 1];
            } else if (MODE == 2) {
                const int kb = col >> 10, key = col & 1023;
                const int h = row0 >> 6, d0 = row0 & 63;
                unsigned long long wv = 0;
                #pragma unroll
                for (int r = 0; r < 4; ++r)
                    wv |= (unsigned long long)bf16r(acc[mi][ni][r]) << (16 * r);
                *(unsigned long long*)(Cb +
                    (((size_t)(kb * 8 + h)) * 1024 + key) * 64 + d0) = wv;
            } else {
                const int kb = row0 >> 10, key0 = row0 & 1023;
                const int h = col >> 6, d = col & 63;
                unsigned long long wv = 0;
                #pragma unroll
                for (int r = 0; r < 4; ++r)
                    wv |= (unsigned long long)bf16r(acc[mi][ni][r]) << (16 * r);
                *(unsigned long long*)(Cb +
                    (((size_t)(kb * 8 + h)) * 64 + d) * 1024 + key0) = wv;
            }
        }
    }
}

// ---------------------------------------------------------------------------
// MFMA flash attention (round-5 structure, known-good): 32x32x16, 128 q/block,
// LDS-staged K/V tiles, register P via shfl_xor(32), no-max softmax.
// l summed from fp32 exps (truncation bias of P ~2^-10 -> <2e-4 abs, in budget)
// ---------------------------------------------------------------------------
#define KS2 72   // Ks/Vs row stride in ushorts (144B, 16B-aligned)

__global__ __launch_bounds__(256)
void attn_mfma32(const unsigned short* __restrict__ qb,
                 const unsigned short* __restrict__ Kb,
                 const unsigned short* __restrict__ Vt,
                 unsigned short* __restrict__ out) {
    __shared__ unsigned short Ks[64 * KS2];   // [key][d]
    __shared__ unsigned short Vs[64 * KS2];   // [d][key]

    const int t = threadIdx.x;
    const int w = t >> 6;
    const int lane = t & 63;
    const int m32 = lane & 31;     // q-col (S^T), key-row (A), d-col (O)
    const int sig = lane >> 5;     // half-lane
    const int n0 = blockIdx.x * 128;
    const int bh = blockIdx.y;
    const int b = bh >> 3, h = bh & 7;

    // Q B-frags: B[n=q=m32][k=d], 4 chunks of K=16
    short8 qf[4];
    {
        const unsigned short* qrow =
            qb + ((size_t)(b * 4096 + n0 + w * 32 + m32)) * 512 + h * 64;
        #pragma unroll
        for (int kc = 0; kc < 4; ++kc)
            qf[kc] = *(const short8*)(qrow + kc * 16 + sig * 8);
    }

    float l_own = 0.f;
    floatx16 O0, O1;
    #pragma unroll
    for (int i = 0; i < 16; ++i) { O0[i] = 0.f; O1[i] = 0.f; }

    const unsigned short* Kg = Kb + (size_t)bh * 1024 * 64;
    const unsigned short* Vg = Vt + (size_t)bh * 64 * 1024;
    const int srow = t >> 2;
    const int sdb  = (t & 3) * 16;

    for (int kt = 0; kt < 16; ++kt) {
        __syncthreads();
        {   // stage K tile [64 key][64 d]
            const unsigned short* src = Kg + ((size_t)(kt * 64 + srow)) * 64 + sdb;
            *(ushort8*)&Ks[srow * KS2 + sdb]     = *(const ushort8*)src;
            *(ushort8*)&Ks[srow * KS2 + sdb + 8] = *(const ushort8*)(src + 8);
        }
        {   // stage V^T tile [64 d][64 key]
            const unsigned short* src = Vg + (size_t)srow * 1024 + kt * 64 + sdb;
            *(ushort8*)&Vs[srow * KS2 + sdb]     = *(const ushort8*)src;
            *(ushort8*)&Vs[srow * KS2 + sdb + 8] = *(const ushort8*)(src + 8);
        }
        __syncthreads();

        // S^T = K·Q^T : two 32-key groups
        floatx16 st0, st1;
        #pragma unroll
        for (int i = 0; i < 16; ++i) { st0[i] = 0.f; st1[i] = 0.f; }
        #pragma unroll
        for (int kc = 0; kc < 4; ++kc) {
            const short8 a0 = *(const short8*)&Ks[m32 * KS2 + kc * 16 + sig * 8];
            st0 = __builtin_amdgcn_mfma_f32_32x32x16_bf16(a0, qf[kc], st0, 0, 0, 0);
            const short8 a1 = *(const short8*)&Ks[(32 + m32) * KS2 + kc * 16 + sig * 8];
            st1 = __builtin_amdgcn_mfma_f32_32x32x16_bf16(a1, qf[kc], st1, 0, 0, 0);
        }

        // p = 2^s, truncated-bf16 pack per reg-quad; l from fp32 exps
        uint2 E[2][4];
        #pragma unroll
        for (int g = 0; g < 2; ++g) {
            #pragma unroll
            for (int qd = 0; qd < 4; ++qd) {
                const float p0 = __builtin_amdgcn_exp2f(g ? st1[qd * 4 + 0] : st0[qd * 4 + 0]);
                const float p1 = __builtin_amdgcn_exp2f(g ? st1[qd * 4 + 1] : st0[qd * 4 + 1]);
                const float p2 = __builtin_amdgcn_exp2f(g ? st1[qd * 4 + 2] : st0[qd * 4 + 2]);
                const float p3 = __builtin_amdgcn_exp2f(g ? st1[qd * 4 + 3] : st0[qd * 4 + 3]);
                E[g][qd].x = __builtin_amdgcn_perm(
                    __float_as_uint(p1), __float_as_uint(p0), 0x07060302u);
                E[g][qd].y = __builtin_amdgcn_perm(
                    __float_as_uint(p3), __float_as_uint(p2), 0x07060302u);
                l_own += (p0 + p1) + (p2 + p3);
            }
        }

        // O += P·V : A-frag per K-chunk via one cross-half exchange.
        #pragma unroll
        for (int kc = 0; kc < 4; ++kc) {
            const int g = kc >> 1, qlo = (kc & 1) * 2;
            const uint2 keep = sig ? E[g][qlo + 1] : E[g][qlo];
            const uint2 send = sig ? E[g][qlo]     : E[g][qlo + 1];
            uint2 got;
            got.x = __shfl_xor(send.x, 32);
            got.y = __shfl_xor(send.y, 32);
            uint4 fr;
            fr.x = sig ? got.x  : keep.x;
            fr.y = sig ? got.y  : keep.y;
            fr.z = sig ? keep.x : got.x;
            fr.w = sig ? keep.y : got.y;
            const short8 pa = *(const short8*)&fr;
            const short8 v0 = *(const short8*)&Vs[m32 * KS2 + kc * 16 + sig * 8];
            O0 = __builtin_amdgcn_mfma_f32_32x32x16_bf16(pa, v0, O0, 0, 0, 0);
            const short8 v1 = *(const short8*)&Vs[(32 + m32) * KS2 + kc * 16 + sig * 8];
            O1 = __builtin_amdgcn_mfma_f32_32x32x16_bf16(pa, v1, O1, 0, 0, 0);
        }
    }

    // combine key-halves of l
    l_own += __shfl_xor(l_own, 32);
    const float inv = 1.0f / l_own;

    float fo0[16], fo1[16];
    #pragma unroll
    for (int r = 0; r < 16; ++r) {
        const float li = __shfl(inv, ((r & 3) + 8 * (r >> 2)) + 4 * sig);
        fo0[r] = O0[r] * li;
        fo1[r] = O1[r] * li;
    }

    // paired u32 bf16 stores: even m32 stores gd=0 regs, odd stores gd=1
    #pragma unroll
    for (int gd = 0; gd < 2; ++gd) {
        unsigned mg[16];
        #pragma unroll
        for (int r = 0; r < 16; ++r) {
            const unsigned own = bf16r(gd ? fo1[r] : fo0[r]);
            const unsigned pt = __shfl_xor(own, 1);
            mg[r] = (m32 & 1) ? (pt | (own << 16)) : (own | (pt << 16));
        }
        if ((m32 & 1) == gd) {
            const int colb = h * 64 + gd * 32 + (m32 & ~1);
            #pragma unroll
            for (int r = 0; r < 16; ++r) {
                const int qrow = (r & 3) + 8 * (r >> 2) + 4 * sig;
                const size_t row = (size_t)(b * 4096 + n0 + w * 32 + qrow);
                *(unsigned*)(out + row * 512 + colb) = mg[r];
            }
        }
    }
}

extern "C" void kernel_launch(void* const* d_in, const int* in_sizes, int n_in,
                              void* d_out, int out_size, void* d_ws, size_t ws_size,
                              hipStream_t stream) {
    const float* x      = (const float*)d_in[0];
    const float* q_w    = (const float*)d_in[1];
    const float* kv_w   = (const float*)d_in[2];
    const float* sr_w   = (const float*)d_in[3];
    const float* sr_b   = (const float*)d_in[4];
    const float* proj_w = (const float*)d_in[5];
    const float* proj_b = (const float*)d_in[6];
    float* out = (float*)d_out;

    // Workspace (ushort = bf16). xb dead after q-gemm -> reused as attb.
    unsigned short* xb   = (unsigned short*)d_ws;               // 16384*512
    unsigned short* attb = xb;
    unsigned short* qb   = xb   + (size_t)16384 * 512;          // 16384*512
    unsigned short* xrb  = qb   + (size_t)16384 * 512;          // 4096*2048
    unsigned short* xsrb = xrb  + (size_t)4096 * 2048;          // 4096*512
    unsigned short* qwb  = xsrb + (size_t)4096 * 512;           // 512*512
    unsigned short* kvwb = qwb  + (size_t)512 * 512;            // 1024*512
    unsigned short* srwb = kvwb + (size_t)1024 * 512;           // 512*2048
    unsigned short* pwb  = srwb + (size_t)512 * 2048;           // 512*512
    unsigned short* Kb   = pwb  + (size_t)512 * 512;            // 32*1024*64
    unsigned short* Vt   = Kb   + (size_t)32 * 1024 * 64;       // 32*64*1024
    // total ~72 MB

    const dim3 blk(256);

    // converts + im2col, one launch
    prep<<<13312, blk, 0, stream>>>(x, q_w, kv_w, sr_w, proj_w,
                                    xb, qwb, kvwb, srwb, pwb, xrb);

    // q = x @ (scaled q_w)^T -> bf16        [1024 blocks]
    gemm_mfma<128, 64, 1><<<dim3(128, 8), blk, 0, stream>>>(
        xb, qwb, nullptr, nullptr, qb, 16384, 512, 512);

    // x_sr = conv(x) + sr_b -> bf16         [512 blocks]
    gemm_mfma<64, 64, 1><<<dim3(64, 8), blk, 0, stream>>>(
        xrb, srwb, sr_b, nullptr, xsrb, 4096, 512, 2048);

    // K = kv_w_K @ x_sr^T -> Kb[bh][key][d] [256 blocks]
    gemm_mfma<128, 64, 2><<<dim3(4, 64), blk, 0, stream>>>(
        kvwb, xsrb, nullptr, nullptr, Kb, 512, 4096, 512);

    // V = x_sr @ kv_w_V^T -> Vt[bh][d][key] [256 blocks]
    gemm_mfma<128, 64, 3><<<dim3(32, 8), blk, 0, stream>>>(
        xsrb, kvwb + (size_t)512 * 512, nullptr, nullptr, Vt, 4096, 512, 512);

    // attention -> bf16 att (aliases xb)
    attn_mfma32<<<dim3(32, 32), blk, 0, stream>>>(qb, Kb, Vt, attb);

    // out = att @ proj_w^T + proj_b -> fp32 [1024 blocks]
    gemm_mfma<128, 64, 0><<<dim3(128, 8), blk, 0, stream>>>(
        attb, pwb, proj_b, out, nullptr, 16384, 512, 512);
}